// Round 16
// baseline (544.482 us; speedup 1.0000x reference)
//
#include <hip/hip_runtime.h>

// ---------------- constants from the reference ----------------
#define B_    4096
#define ACT   768
#define DICT  12288
#define KTOP  512
#define NDMAX 1024          // N_DEAD
#define AUX_PEN  0.03125f
#define SOFT_PEN 0.01f
#define L1_CO    0.001f
#define EPS_     1e-5f
#define NBLK_FE  1536       // final_elem blocks (4096*768 / (256*8))
#define PLANE    (B_ * ACT) // 3145728
#define SPLITK2  4          // gemm2 split-K
#define SPLITK3  2          // gemm3 split-K

typedef __attribute__((ext_vector_type(4))) float f32x4;
typedef __attribute__((ext_vector_type(4))) unsigned int u32x4;
typedef __attribute__((ext_vector_type(8))) short short8;
typedef __attribute__((ext_vector_type(8))) __bf16 bf8_t;

// ---------------- small helpers ----------------
__device__ __forceinline__ float b2f(unsigned short u) {
    return __uint_as_float(((unsigned)u) << 16);
}
__device__ __forceinline__ unsigned short f2b(float f) {
    unsigned u = __float_as_uint(f);
    unsigned r = (u + 0x7FFFu + ((u >> 16) & 1u)) >> 16;   // RNE
    return (unsigned short)r;
}

__device__ __forceinline__ float wredsum(float v) {
#pragma unroll
    for (int o = 32; o; o >>= 1) v += __shfl_down(v, o);
    return v;
}
__device__ __forceinline__ float wredmax(float v) {
#pragma unroll
    for (int o = 32; o; o >>= 1) v = fmaxf(v, __shfl_down(v, o));
    return v;
}
__device__ __forceinline__ int wredsumi(int v) {
#pragma unroll
    for (int o = 32; o; o >>= 1) v += __shfl_down(v, o);
    return v;
}
// block = 256 threads = 4 waves; result broadcast to all threads
__device__ __forceinline__ float bredsum(float v, float* sh) {
    int lane = threadIdx.x & 63, w = threadIdx.x >> 6;
    v = wredsum(v);
    __syncthreads();
    if (!lane) sh[w] = v;
    __syncthreads();
    return sh[0] + sh[1] + sh[2] + sh[3];
}
__device__ __forceinline__ float bredmax(float v, float* sh) {
    int lane = threadIdx.x & 63, w = threadIdx.x >> 6;
    v = wredmax(v);
    __syncthreads();
    if (!lane) sh[w] = v;
    __syncthreads();
    return fmaxf(fmaxf(sh[0], sh[1]), fmaxf(sh[2], sh[3]));
}
__device__ __forceinline__ int bredsumi(int v, int* sh) {
    int lane = threadIdx.x & 63, w = threadIdx.x >> 6;
    v = wredsumi(v);
    __syncthreads();
    if (!lane) sh[w] = v;
    __syncthreads();
    return sh[0] + sh[1] + sh[2] + sh[3];
}

__device__ __forceinline__ void gload16(const void* g, const void* lds_base) {
    __builtin_amdgcn_global_load_lds((const __attribute__((address_space(1))) void*)g,
                                     (__attribute__((address_space(3))) void*)lds_base,
                                     16, 0, 0);
}

// ---------------- 1. row normalization ----------------
__global__ __launch_bounds__(256) void norm_kernel(
    const float* __restrict__ x, float* __restrict__ xn,
    unsigned short* __restrict__ xnb, float* __restrict__ xstd)
{
    __shared__ float sh[4];
    const int row = blockIdx.x, t = threadIdx.x;
    const float* xr = x + (size_t)row * ACT;
    float v0 = xr[t], v1 = xr[t + 256], v2 = xr[t + 512];
    float s = bredsum(v0 + v1 + v2, sh);
    float mean = s * (1.0f / ACT);
    v0 -= mean; v1 -= mean; v2 -= mean;
    float s2 = bredsum(v0 * v0 + v1 * v1 + v2 * v2, sh);
    float sd = sqrtf(s2 / (float)(ACT - 1));
    float inv = 1.0f / (sd + EPS_);
    v0 *= inv; v1 *= inv; v2 *= inv;
    size_t base = (size_t)row * ACT;
    xn[base + t] = v0; xn[base + t + 256] = v1; xn[base + t + 512] = v2;
    xnb[base + t] = f2b(v0); xnb[base + t + 256] = f2b(v1); xnb[base + t + 512] = f2b(v2);
    if (!t) xstd[row] = sd;
}

// ---------------- 2. f32 [R][C] -> bf16 [C][R] transpose-convert ----------------
__global__ __launch_bounds__(256) void transpose_bf16(
    const float* __restrict__ in, unsigned short* __restrict__ out, int R, int C)
{
    __shared__ float tile[64][65];
    const int c0 = blockIdx.x * 64, r0 = blockIdx.y * 64;
    const int t = threadIdx.x;
#pragma unroll
    for (int i = 0; i < 16; i++) {
        int lin = t + i * 256;
        int r = lin >> 6, c = lin & 63;
        tile[r][c] = in[(size_t)(r0 + r) * C + c0 + c];
    }
    __syncthreads();
#pragma unroll
    for (int i = 0; i < 16; i++) {
        int lin = t + i * 256;
        int cc = lin >> 6, rr = lin & 63;
        out[(size_t)(c0 + cc) * R + r0 + rr] = f2b(tile[rr][cc]);
    }
}

// ---------------- 3. cvec[j] = b_enc[j] - b_dec . W_enc[:,j] ----------------
__global__ __launch_bounds__(256) void cvec_kernel(
    const float* __restrict__ benc, const float* __restrict__ bdec,
    const float* __restrict__ wenc, float* __restrict__ cvec)
{
    int j = blockIdx.x * 256 + threadIdx.x;
    float acc = 0.f;
    for (int k = 0; k < ACT; k++) acc += bdec[k] * wenc[(size_t)k * DICT + j];
    cvec[j] = benc[j] - acc;
}

// ---------------- 4. dead feature scan (dtype-robust) ----------------
__global__ __launch_bounds__(256) void dead_scan(
    const void* __restrict__ dead_raw, int* __restrict__ dead_list, int* __restrict__ ndp)
{
    __shared__ int cnt[256];
    const unsigned char* u8 = (const unsigned char*)dead_raw;
    const unsigned* u32p = (const unsigned*)dead_raw;
    unsigned w0 = u32p[0];
    int mode;                 // 0=int32, 1=u8, 2=f32
    if (w0 == 0x01010101u) mode = 1;
    else if (w0 == 0x3F800000u) mode = 2;
    else if (w0 == 1u) mode = 0;
    else mode = (u8[1] | u8[2] | u8[3]) ? 1 : 0;

    const int t = threadIdx.x;
    const int per = DICT / 256;     // 48
    const int base = t * per;
    int c = 0;
    for (int i = 0; i < per; i++) {
        int j = base + i;
        bool d = (mode == 1) ? (u8[j] != 0)
               : (mode == 2) ? (((const float*)dead_raw)[j] != 0.f)
                             : (((const int*)dead_raw)[j] != 0);
        c += d ? 1 : 0;
    }
    cnt[t] = c;
    __syncthreads();
    if (!t) {
        int run = 0;
        for (int i = 0; i < 256; i++) { int v = cnt[i]; cnt[i] = run; run += v; }
        *ndp = run;
    }
    __syncthreads();
    int o = cnt[t];
    for (int i = 0; i < per; i++) {
        int j = base + i;
        bool d = (mode == 1) ? (u8[j] != 0)
               : (mode == 2) ? (((const float*)dead_raw)[j] != 0.f)
                             : (((const int*)dead_raw)[j] != 0);
        if (d) dead_list[o++] = j;
    }
}

// ---------------- 5. GEMM1 (2-phase dbuf, BK=32) — round-10 proven form ----------------
__global__ __launch_bounds__(256) void gemm1_kernel(
    const unsigned short* __restrict__ A, const unsigned short* __restrict__ Bt,
    const float* __restrict__ cvec, unsigned short* __restrict__ actspre)
{
    __shared__ __align__(16) unsigned short As[2][128 * 32];
    __shared__ __align__(16) unsigned short Bs[2][128 * 32];
    const int tid = threadIdx.x, lane = tid & 63, wave = tid >> 6;
    const int wr = wave >> 1, wc = wave & 1;
    const int lr = lane & 15, lg = lane >> 4;
    // XCD-grouped remap (bijective on [0,3072))
    const int flat = blockIdx.x;
    const int xcd = flat & 7, j = flat >> 3;       // j 0..383
    const int col0 = (xcd * 12 + (j >> 5)) * 128;  // col tile 0..95
    const int row0 = (j & 31) * 128;               // row panel 0..31
    const int nsteps = ACT / 32;      // 24
    f32x4 acc[4][4] = {};

    auto stage = [&](int kt, int b) {
#pragma unroll
        for (int i = 0; i < 2; i++) {
            int c = wave * 2 + i;
            int o = c * 1024;
            int ol = o + lane * 16;
            int r = ol >> 6;
            int cb = (ol & 63) ^ (((r >> 1) & 3) << 4);
            gload16((const char*)A + (size_t)(row0 + r) * (ACT * 2) + kt * 2 + cb,
                    (const char*)As[b] + o);
            gload16((const char*)Bt + (size_t)(col0 + r) * (ACT * 2) + kt * 2 + cb,
                    (const char*)Bs[b] + o);
        }
    };

    stage(0, 0);
    __syncthreads();
    int cur = 0;
    for (int t = 0; t < nsteps; ++t) {
        const int nxt = cur ^ 1;
        if (t + 1 < nsteps) stage((t + 1) * 32, nxt);
        bf8_t af[4], bfr[4];
#pragma unroll
        for (int m = 0; m < 4; m++) {
            int row = wr * 64 + m * 16 + lr;
            af[m] = *(const bf8_t*)((const char*)As[cur] + row * 64 + ((lg * 16) ^ (((row >> 1) & 3) << 4)));
        }
#pragma unroll
        for (int n = 0; n < 4; n++) {
            int col = wc * 64 + n * 16 + lr;
            bfr[n] = *(const bf8_t*)((const char*)Bs[cur] + col * 64 + ((lg * 16) ^ (((col >> 1) & 3) << 4)));
        }
#pragma unroll
        for (int m = 0; m < 4; m++)
#pragma unroll
            for (int n = 0; n < 4; n++)
                acc[m][n] = __builtin_amdgcn_mfma_f32_16x16x32_bf16(af[m], bfr[n], acc[m][n], 0, 0, 0);
        __syncthreads();
        cur = nxt;
    }
#pragma unroll
    for (int m = 0; m < 4; m++) {
        int row = row0 + wr * 64 + m * 16 + lg * 4;
#pragma unroll
        for (int n = 0; n < 4; n++) {
            int col = col0 + wc * 64 + n * 16 + lr;
            float cadd = cvec[col];
#pragma unroll
            for (int r = 0; r < 4; r++) {
                float v = acc[m][n][r] + cadd;
                actspre[(size_t)(row + r) * DICT + col] = f2b(v);
            }
        }
    }
}

// ---------------- 6. row softmax stats + l1/l0 + top-K + aux A-matrices + out_thr ----------------
__global__ __launch_bounds__(256) void softrow_kernel(
    unsigned short* __restrict__ actspre, const float* __restrict__ qtp,
    const int* __restrict__ dead_list, const int* __restrict__ ndp,
    unsigned short* __restrict__ asoft, unsigned short* __restrict__ aaux,
    float* __restrict__ l1row, float* __restrict__ l0row,
    float* __restrict__ out_thr)
{
    __shared__ __align__(16) unsigned short rowv[DICT];
    __shared__ float shf[4];
    __shared__ int shi[4];
    const int t = threadIdx.x, row = blockIdx.x;
    unsigned short* src = actspre + (size_t)row * DICT;
    float* othr = out_thr + (size_t)row * DICT;
    short8 v[6];
    float mx = -1e30f;
#pragma unroll
    for (int i = 0; i < 6; i++) {
        v[i] = *(const short8*)(src + i * 2048 + t * 8);
        *(short8*)(rowv + i * 2048 + t * 8) = v[i];
#pragma unroll
        for (int e = 0; e < 8; e++) mx = fmaxf(mx, b2f((unsigned short)v[i][e]));
    }
    mx = bredmax(mx, shf);
    const float qt = fmaxf(qtp[0], 0.0f);
    float se = 0.f, l1 = 0.f, l0 = 0.f;
#pragma unroll
    for (int i = 0; i < 6; i++) {
        short8 tvv;
        float tvf[8];
#pragma unroll
        for (int e = 0; e < 8; e++) {
            float f = b2f((unsigned short)v[i][e]);
            se += __expf(f - mx);
            float a = fmaxf(f, 0.f);
            float tv = (a > qt) ? a : 0.f;
            l1 += tv;
            l0 += (tv > 0.f) ? 1.f : 0.f;
            tvv[e] = (tv > 0.f) ? v[i][e] : (short)0;   // thresholded bf16 (exact bits)
            tvf[e] = tv;
        }
        *(short8*)(src + i * 2048 + t * 8) = tvv;       // in-place write-back for gemm2
        float* od = othr + i * 2048 + t * 8;
        *(f32x4*)od       = (f32x4){ tvf[0], tvf[1], tvf[2], tvf[3] };
        *(f32x4*)(od + 4) = (f32x4){ tvf[4], tvf[5], tvf[6], tvf[7] };
    }
    se = bredsum(se, shf);
    l1 = bredsum(l1, shf);
    l0 = bredsum(l0, shf);
    if (!t) { l1row[row] = l1; l0row[row] = l0; }

    float inv64 = 64.0f / se;
    int nd = *ndp; if (nd > NDMAX) nd = NDMAX;
    unsigned k16[4]; float av_[4];
#pragma unroll
    for (int i = 0; i < 4; i++) {
        int k = t + i * 256;
        float f = 0.f;
        if (k < nd) {
            int idx = dead_list[k];
            f = b2f(rowv[idx]);
            asoft[(size_t)row * NDMAX + k] = f2b(f * __expf(f - mx) * inv64);
        } else {
            asoft[(size_t)row * NDMAX + k] = 0;
        }
        float a = (k < nd) ? fmaxf(f, 0.f) : 0.f;
        av_[i] = a;
        k16[i] = __float_as_uint(a) >> 16;   // bf16-derived: low 16 bits are zero
    }
    unsigned lo = 0u, hi = 0x7F80u;
    while (hi - lo > 1u) {
        unsigned mid = (lo + hi) >> 1;
        int c = 0;
#pragma unroll
        for (int i = 0; i < 4; i++) c += (k16[i] >= mid) ? 1 : 0;
        c = bredsumi(c, shi);
        if (c >= KTOP) lo = mid; else hi = mid;
    }
#pragma unroll
    for (int i = 0; i < 4; i++) {
        int k = t + i * 256;
        aaux[(size_t)row * NDMAX + k] = f2b((k16[i] >= lo) ? av_[i] : 0.f);
    }
}

// ---------------- 7. gather dead rows of W_dec^T -> [768][NDMAX] ----------------
__global__ __launch_bounds__(256) void wdead_gather(
    const unsigned short* __restrict__ wdec_t, const int* __restrict__ dead_list,
    const int* __restrict__ ndp, unsigned short* __restrict__ wdead)
{
    int n = blockIdx.x;
    int nd = *ndp; if (nd > NDMAX) nd = NDMAX;
    for (int k = threadIdx.x; k < NDMAX; k += 256)
        wdead[(size_t)n * NDMAX + k] = (k < nd) ? wdec_t[(size_t)n * DICT + dead_list[k]] : 0;
}

// ---------------- 8. GEMM2 (split-K=4, 64x128 M-SPLIT tiles, BK=32, 2-phase dbuf unroll-2) ----------------
// M-split (not N-split): each block owns 64 rows x 128 cols. A-staging total is UNCHANGED
// (the round-4 failure was N-split duplicating A); only B staging doubles, and B (19 MB)
// is L2-resident. Grid 1536 = 6 blocks/CU, LDS 24 KB, acc regs halved.
// 256 groups = (64 row-panels x 4 z), 6 col members each, XCD-grouped.
__global__ __launch_bounds__(256) void gemm2_kernel(
    const unsigned short* __restrict__ Apre, const unsigned short* __restrict__ Bt,
    float* __restrict__ pxrA, float* __restrict__ pxrB)
{
    __shared__ __align__(16) unsigned short As[2][64 * 32];    // 2 x 4 KB
    __shared__ __align__(16) unsigned short Bs[2][128 * 32];   // 2 x 8 KB
    const int tid = threadIdx.x, lane = tid & 63, wave = tid >> 6;
    const int wr = wave >> 1, wc = wave & 1;       // 2M x 2N waves over 64x128
    const int lr = lane & 15, lg = lane >> 4;
    const int flat = blockIdx.x;
    const int xcd = flat & 7, s = flat >> 3;       // s 0..191
    const int q = s / 6, m_ = s - 6 * q;           // m_ 0..5 = col tile
    const int g = q * 8 + xcd;                     // 0..255 = (row panel, k chunk)
    const int col0 = m_ * 128;
    const int row0 = (g & 63) * 64;                // 64 row panels
    const int zidx = g >> 6;                       // 0..3
    const int kbase = zidx * (DICT / SPLITK2);
    const int nsteps = (DICT / SPLITK2) / 32;      // 96 (even)
    f32x4 acc[2][4] = {};

    auto stage = [&](int kt, int b) {
        {   // A: 64 rows x 32 bf16 = 4 KB -> 1 chunk per wave
            int o = wave * 1024;
            int ol = o + lane * 16;
            int r = ol >> 6;
            int cb = (ol & 63) ^ (((r >> 1) & 3) << 4);
            gload16((const char*)Apre + (size_t)(row0 + r) * (DICT * 2) + (size_t)kt * 2 + cb,
                    (const char*)As[b] + o);
        }
#pragma unroll
        for (int i = 0; i < 2; i++) {   // B: 128 cols x 32 bf16 = 8 KB -> 2 chunks per wave
            int c = wave * 2 + i;
            int o = c * 1024;
            int ol = o + lane * 16;
            int r = ol >> 6;
            int cb = (ol & 63) ^ (((r >> 1) & 3) << 4);
            gload16((const char*)Bt + (size_t)(col0 + r) * (DICT * 2) + (size_t)kt * 2 + cb,
                    (const char*)Bs[b] + o);
        }
    };
    auto compute = [&](int b) {
        bf8_t af[2], bfr[4];
#pragma unroll
        for (int m = 0; m < 2; m++) {
            int row = wr * 32 + m * 16 + lr;
            af[m] = *(const bf8_t*)((const char*)As[b] + row * 64 + ((lg * 16) ^ (((row >> 1) & 3) << 4)));
        }
#pragma unroll
        for (int n = 0; n < 4; n++) {
            int col = wc * 64 + n * 16 + lr;
            bfr[n] = *(const bf8_t*)((const char*)Bs[b] + col * 64 + ((lg * 16) ^ (((col >> 1) & 3) << 4)));
        }
#pragma unroll
        for (int m = 0; m < 2; m++)
#pragma unroll
            for (int n = 0; n < 4; n++)
                acc[m][n] = __builtin_amdgcn_mfma_f32_16x16x32_bf16(af[m], bfr[n], acc[m][n], 0, 0, 0);
    };

    stage(kbase, 0);
    __syncthreads();
    for (int t = 0; t < nsteps; t += 2) {
        stage(kbase + (t + 1) * 32, 1);    // t+1 < nsteps always (nsteps even)
        compute(0);
        __syncthreads();
        if (t + 2 < nsteps) stage(kbase + (t + 2) * 32, 0);
        compute(1);
        __syncthreads();
    }
    float* out = (zidx < 2) ? (pxrA + (size_t)zidx * PLANE)
                            : (pxrB + (size_t)(zidx - 2) * PLANE);
#pragma unroll
    for (int m = 0; m < 2; m++) {
        int row = row0 + wr * 32 + m * 16 + lg * 4;
#pragma unroll
        for (int n = 0; n < 4; n++) {
            int col = col0 + wc * 64 + n * 16 + lr;
#pragma unroll
            for (int r = 0; r < 4; r++)
                out[(size_t)(row + r) * ACT + col] = acc[m][n][r];
        }
    }
}

// ---------------- 9. GEMM3 (dual A, split-K, BK=32, 2-phase dbuf unroll-2) — round-15 form ----------------
__global__ __launch_bounds__(256) void gemm3_kernel(
    const unsigned short* __restrict__ A1, const unsigned short* __restrict__ A2,
    const unsigned short* __restrict__ Bt,
    float* __restrict__ praux, float* __restrict__ prsoft)
{
    __shared__ __align__(16) unsigned short A1s[2][128 * 32];
    __shared__ __align__(16) unsigned short A2s[2][128 * 32];
    __shared__ __align__(16) unsigned short Bs[2][128 * 32];
    const int tid = threadIdx.x, lane = tid & 63, wave = tid >> 6;
    const int wr = wave >> 1, wc = wave & 1;
    const int lr = lane & 15, lg = lane >> 4;
    const int flat = blockIdx.x;
    const int xcd = flat & 7, s = flat >> 3;
    const int q = s / 6, m_ = s - 6 * q;
    const int g = q * 8 + xcd;            // group 0..63
    const int col0 = m_ * 128;
    const int row0 = (g & 31) * 128;
    const int zidx = g >> 5;
    const int kbase = zidx * (NDMAX / SPLITK3);
    const int nsteps = (NDMAX / SPLITK3) / 32;   // 16 (even)
    f32x4 acc1[4][4] = {}, acc2[4][4] = {};

    auto stage = [&](int kt, int b) {
#pragma unroll
        for (int i = 0; i < 2; i++) {
            int c = wave * 2 + i;
            int o = c * 1024;
            int ol = o + lane * 16;
            int r = ol >> 6;
            int cb = (ol & 63) ^ (((r >> 1) & 3) << 4);
            gload16((const char*)A1 + (size_t)(row0 + r) * (NDMAX * 2) + (size_t)kt * 2 + cb,
                    (const char*)A1s[b] + o);
            gload16((const char*)A2 + (size_t)(row0 + r) * (NDMAX * 2) + (size_t)kt * 2 + cb,
                    (const char*)A2s[b] + o);
            gload16((const char*)Bt + (size_t)(col0 + r) * (NDMAX * 2) + (size_t)kt * 2 + cb,
                    (const char*)Bs[b] + o);
        }
    };
    auto compute = [&](int b) {
        bf8_t a1f[4], a2f[4], bfr[4];
#pragma unroll
        for (int m = 0; m < 4; m++) {
            int row = wr * 64 + m * 16 + lr;
            int bo = (lg * 16) ^ (((row >> 1) & 3) << 4);
            a1f[m] = *(const bf8_t*)((const char*)A1s[b] + row * 64 + bo);
            a2f[m] = *(const bf8_t*)((const char*)A2s[b] + row * 64 + bo);
        }
#pragma unroll
        for (int n = 0; n < 4; n++) {
            int col = wc * 64 + n * 16 + lr;
            bfr[n] = *(const bf8_t*)((const char*)Bs[b] + col * 64 + ((lg * 16) ^ (((col >> 1) & 3) << 4)));
        }
#pragma unroll
        for (int m = 0; m < 4; m++)
#pragma unroll
            for (int n = 0; n < 4; n++) {
                acc1[m][n] = __builtin_amdgcn_mfma_f32_16x16x32_bf16(a1f[m], bfr[n], acc1[m][n], 0, 0, 0);
                acc2[m][n] = __builtin_amdgcn_mfma_f32_16x16x32_bf16(a2f[m], bfr[n], acc2[m][n], 0, 0, 0);
            }
    };

    stage(kbase, 0);
    __syncthreads();
    for (int t = 0; t < nsteps; t += 2) {
        stage(kbase + (t + 1) * 32, 1);
        compute(0);
        __syncthreads();
        if (t + 2 < nsteps) stage(kbase + (t + 2) * 32, 0);
        compute(1);
        __syncthreads();
    }
    float* o1 = praux  + (size_t)zidx * PLANE;
    float* o2 = prsoft + (size_t)zidx * PLANE;
#pragma unroll
    for (int m = 0; m < 4; m++) {
        int row = row0 + wr * 64 + m * 16 + lg * 4;
#pragma unroll
        for (int n = 0; n < 4; n++) {
            int col = col0 + wc * 64 + n * 16 + lr;
#pragma unroll
            for (int r = 0; r < 4; r++) {
                size_t idx = (size_t)(row + r) * ACT + col;
                o1[idx] = acc1[m][n][r];
                o2[idx] = acc2[m][n][r];
            }
        }
    }
}

// ---------------- 10. split-K reduce + elementwise epilogue + partial loss sums ----------------
__global__ __launch_bounds__(256) void final_elem(
    const float* __restrict__ pxrA, const float* __restrict__ pxrB,
    const float* __restrict__ praux, const float* __restrict__ prsoft,
    const float* __restrict__ xn, const float* __restrict__ xstd,
    const float* __restrict__ bdec,
    float* __restrict__ sae_out, float* __restrict__ partials)
{
    __shared__ float sh[4];
    const int t = threadIdx.x, blk = blockIdx.x;
    const int base = blk * 2048;
    float s2 = 0.f, sa = 0.f, ss = 0.f;
#pragma unroll
    for (int i = 0; i < 8; i++) {
        int idx = base + t + i * 256;
        int row = idx / ACT;
        int col = idx - row * ACT;
        float bd = bdec[col];
        float r  = pxrA[idx] + pxrA[PLANE + idx] + pxrB[idx] + pxrB[PLANE + idx] + bd;
        float ra = praux[idx] + praux[PLANE + idx] + bd;
        float rs = prsoft[idx] + prsoft[PLANE + idx] + bd;
        float xv = xn[idx];
        float resid = xv - r;
        float da = ra - resid;
        float dsf = rs - resid;
        s2 += resid * resid;
        sa += da * da;
        ss += dsf * dsf;
        sae_out[idx] = r * xstd[row] + xv;
    }
    s2 = bredsum(s2, sh);
    sa = bredsum(sa, sh);
    ss = bredsum(ss, sh);
    if (!t) {
        partials[blk] = s2;
        partials[NBLK_FE + blk] = sa;
        partials[2 * NBLK_FE + blk] = ss;
    }
}

// ---------------- 11. final scalars ----------------
__global__ __launch_bounds__(256) void final_scalar(
    const float* __restrict__ partials, const float* __restrict__ l1row,
    const float* __restrict__ l0row, const int* __restrict__ ndp,
    float* __restrict__ out_sc)
{
    __shared__ float sh[4];
    const int t = threadIdx.x;
    float s2 = 0.f, sa = 0.f, ss = 0.f;
    for (int i = t; i < NBLK_FE; i += 256) {
        s2 += partials[i];
        sa += partials[NBLK_FE + i];
        ss += partials[2 * NBLK_FE + i];
    }
    s2 = bredsum(s2, sh);
    sa = bredsum(sa, sh);
    ss = bredsum(ss, sh);
    float l1 = 0.f, l0 = 0.f;
    for (int i = t; i < B_; i += 256) { l1 += l1row[i]; l0 += l0row[i]; }
    l1 = bredsum(l1, sh);
    l0 = bredsum(l0, sh);
    if (!t) {
        const float n = (float)B_ * (float)ACT;
        float l2   = s2 / n;
        float l2a  = AUX_PEN  * (sa / n);
        float l2s  = SOFT_PEN * (ss / n);
        float l1n  = l1 / (float)B_;
        float l1l  = L1_CO * l1n;
        float l0n  = l0 / (float)B_;
        float loss = l2 + l1l + l2a + l2s;
        out_sc[0] = loss;
        out_sc[1] = l2;
        out_sc[2] = l1l;
        out_sc[3] = l0n;
        out_sc[4] = l1n;
        out_sc[5] = l2a;
        out_sc[6] = l2s;
        out_sc[7] = (float)(*ndp);
    }
}

// ---------------- host launch ----------------
extern "C" void kernel_launch(void* const* d_in, const int* in_sizes, int n_in,
                              void* d_out, int out_size, void* d_ws, size_t ws_size,
                              hipStream_t stream)
{
    const float* x    = (const float*)d_in[0];
    const float* Wenc = (const float*)d_in[1];
    const float* Wdec = (const float*)d_in[2];
    const float* benc = (const float*)d_in[3];
    const float* bdec = (const float*)d_in[4];
    const float* qtp  = (const float*)d_in[5];
    const void*  dead = d_in[6];

    float* out_sae = (float*)d_out;                         // [B_ * ACT]
    float* out_thr = out_sae + (size_t)B_ * ACT;            // [B_ * DICT]
    float* out_sc  = out_thr + (size_t)B_ * DICT;           // [8]

    char* w = (char*)d_ws;
    auto alloc = [&](size_t bytes) -> char* {
        char* p = w;
        w += (bytes + 255) & ~(size_t)255;
        return p;
    };
    float*          xn      = (float*)alloc((size_t)B_ * ACT * 4);
    // xnb and wenc_t are contiguous, dead after gemm1; combined 25,165,824 B = pxr planes 0,1
    unsigned short* xnb     = (unsigned short*)alloc((size_t)B_ * ACT * 2);
    unsigned short* wenc_t  = (unsigned short*)alloc((size_t)DICT * ACT * 2);
    unsigned short* wdec_t  = (unsigned short*)alloc((size_t)ACT * DICT * 2);
    float*          cvec    = (float*)alloc((size_t)DICT * 4);
    unsigned short* actspre = (unsigned short*)alloc((size_t)B_ * DICT * 2);  // 100.66 MB
    unsigned short* asoft   = (unsigned short*)alloc((size_t)B_ * NDMAX * 2);
    unsigned short* aaux    = (unsigned short*)alloc((size_t)B_ * NDMAX * 2);
    unsigned short* wdead   = (unsigned short*)alloc((size_t)ACT * NDMAX * 2);
    float*          xstd    = (float*)alloc((size_t)B_ * 4);
    float*          l1row   = (float*)alloc((size_t)B_ * 4);
    float*          l0row   = (float*)alloc((size_t)B_ * 4);
    float*          partials= (float*)alloc((size_t)3 * NBLK_FE * 4);
    int*            dlist   = (int*)alloc((size_t)DICT * 4);
    int*            ndp     = (int*)alloc(256);
    float*          pxrB    = (float*)alloc((size_t)2 * PLANE * 4);   // pxr planes 2,3

    float* pxrA = (float*)xnb;   // pxr planes 0,1 (xnb+wenc_t, dead after gemm1)
    // gemm3 partial planes alias actspre (gemm3 runs after gemm2's last actspre read)
    float* praux  = (float*)actspre;
    float* prsoft = praux + (size_t)SPLITK3 * PLANE;

    norm_kernel<<<B_, 256, 0, stream>>>(x, xn, xnb, xstd);
    transpose_bf16<<<dim3(DICT / 64, ACT / 64), 256, 0, stream>>>(Wenc, wenc_t, ACT, DICT);
    transpose_bf16<<<dim3(ACT / 64, DICT / 64), 256, 0, stream>>>(Wdec, wdec_t, DICT, ACT);
    cvec_kernel<<<DICT / 256, 256, 0, stream>>>(benc, bdec, Wenc, cvec);
    dead_scan<<<1, 256, 0, stream>>>(dead, dlist, ndp);
    gemm1_kernel<<<3072, 256, 0, stream>>>(xnb, wenc_t, cvec, actspre);
    softrow_kernel<<<B_, 256, 0, stream>>>(actspre, qtp, dlist, ndp, asoft, aaux, l1row, l0row, out_thr);
    wdead_gather<<<ACT, 256, 0, stream>>>(wdec_t, dlist, ndp, wdead);
    gemm2_kernel<<<1536, 256, 0, stream>>>(actspre, wdec_t, pxrA, pxrB);
    gemm3_kernel<<<384, 256, 0, stream>>>(aaux, asoft, wdead, praux, prsoft);
    final_elem<<<NBLK_FE, 256, 0, stream>>>(pxrA, pxrB, praux, prsoft, xn, xstd, bdec, out_sae, partials);
    final_scalar<<<1, 256, 0, stream>>>(partials, l1row, l0row, ndp, out_sc);
}

// Round 17
// 474.644 us; speedup vs baseline: 1.1471x; 1.1471x over previous
//
#include <hip/hip_runtime.h>

// ---------------- constants from the reference ----------------
#define B_    4096
#define ACT   768
#define DICT  12288
#define KTOP  512
#define NDMAX 1024          // N_DEAD
#define AUX_PEN  0.03125f
#define SOFT_PEN 0.01f
#define L1_CO    0.001f
#define EPS_     1e-5f
#define NBLK_FE  1536       // final_elem blocks (4096*768 / (256*8))
#define PLANE    (B_ * ACT) // 3145728
#define SPLITK2  4          // gemm2 split-K
#define SPLITK3  2          // gemm3 split-K

typedef __attribute__((ext_vector_type(4))) float f32x4;
typedef __attribute__((ext_vector_type(4))) unsigned int u32x4;
typedef __attribute__((ext_vector_type(8))) short short8;
typedef __attribute__((ext_vector_type(8))) __bf16 bf8_t;

// ---------------- small helpers ----------------
__device__ __forceinline__ float b2f(unsigned short u) {
    return __uint_as_float(((unsigned)u) << 16);
}
__device__ __forceinline__ unsigned short f2b(float f) {
    unsigned u = __float_as_uint(f);
    unsigned r = (u + 0x7FFFu + ((u >> 16) & 1u)) >> 16;   // RNE
    return (unsigned short)r;
}

__device__ __forceinline__ float wredsum(float v) {
#pragma unroll
    for (int o = 32; o; o >>= 1) v += __shfl_down(v, o);
    return v;
}
__device__ __forceinline__ float wredmax(float v) {
#pragma unroll
    for (int o = 32; o; o >>= 1) v = fmaxf(v, __shfl_down(v, o));
    return v;
}
__device__ __forceinline__ int wredsumi(int v) {
#pragma unroll
    for (int o = 32; o; o >>= 1) v += __shfl_down(v, o);
    return v;
}
// block = 256 threads = 4 waves; result broadcast to all threads
__device__ __forceinline__ float bredsum(float v, float* sh) {
    int lane = threadIdx.x & 63, w = threadIdx.x >> 6;
    v = wredsum(v);
    __syncthreads();
    if (!lane) sh[w] = v;
    __syncthreads();
    return sh[0] + sh[1] + sh[2] + sh[3];
}
__device__ __forceinline__ float bredmax(float v, float* sh) {
    int lane = threadIdx.x & 63, w = threadIdx.x >> 6;
    v = wredmax(v);
    __syncthreads();
    if (!lane) sh[w] = v;
    __syncthreads();
    return fmaxf(fmaxf(sh[0], sh[1]), fmaxf(sh[2], sh[3]));
}
__device__ __forceinline__ int bredsumi(int v, int* sh) {
    int lane = threadIdx.x & 63, w = threadIdx.x >> 6;
    v = wredsumi(v);
    __syncthreads();
    if (!lane) sh[w] = v;
    __syncthreads();
    return sh[0] + sh[1] + sh[2] + sh[3];
}

__device__ __forceinline__ void gload16(const void* g, const void* lds_base) {
    __builtin_amdgcn_global_load_lds((const __attribute__((address_space(1))) void*)g,
                                     (__attribute__((address_space(3))) void*)lds_base,
                                     16, 0, 0);
}

// ---------------- 1. row normalization ----------------
__global__ __launch_bounds__(256) void norm_kernel(
    const float* __restrict__ x, float* __restrict__ xn,
    unsigned short* __restrict__ xnb, float* __restrict__ xstd)
{
    __shared__ float sh[4];
    const int row = blockIdx.x, t = threadIdx.x;
    const float* xr = x + (size_t)row * ACT;
    float v0 = xr[t], v1 = xr[t + 256], v2 = xr[t + 512];
    float s = bredsum(v0 + v1 + v2, sh);
    float mean = s * (1.0f / ACT);
    v0 -= mean; v1 -= mean; v2 -= mean;
    float s2 = bredsum(v0 * v0 + v1 * v1 + v2 * v2, sh);
    float sd = sqrtf(s2 / (float)(ACT - 1));
    float inv = 1.0f / (sd + EPS_);
    v0 *= inv; v1 *= inv; v2 *= inv;
    size_t base = (size_t)row * ACT;
    xn[base + t] = v0; xn[base + t + 256] = v1; xn[base + t + 512] = v2;
    xnb[base + t] = f2b(v0); xnb[base + t + 256] = f2b(v1); xnb[base + t + 512] = f2b(v2);
    if (!t) xstd[row] = sd;
}

// ---------------- 2. f32 [R][C] -> bf16 [C][R] transpose-convert ----------------
__global__ __launch_bounds__(256) void transpose_bf16(
    const float* __restrict__ in, unsigned short* __restrict__ out, int R, int C)
{
    __shared__ float tile[64][65];
    const int c0 = blockIdx.x * 64, r0 = blockIdx.y * 64;
    const int t = threadIdx.x;
#pragma unroll
    for (int i = 0; i < 16; i++) {
        int lin = t + i * 256;
        int r = lin >> 6, c = lin & 63;
        tile[r][c] = in[(size_t)(r0 + r) * C + c0 + c];
    }
    __syncthreads();
#pragma unroll
    for (int i = 0; i < 16; i++) {
        int lin = t + i * 256;
        int cc = lin >> 6, rr = lin & 63;
        out[(size_t)(c0 + cc) * R + r0 + rr] = f2b(tile[rr][cc]);
    }
}

// ---------------- 3. cvec[j] = b_enc[j] - b_dec . W_enc[:,j] ----------------
__global__ __launch_bounds__(256) void cvec_kernel(
    const float* __restrict__ benc, const float* __restrict__ bdec,
    const float* __restrict__ wenc, float* __restrict__ cvec)
{
    int j = blockIdx.x * 256 + threadIdx.x;
    float acc = 0.f;
    for (int k = 0; k < ACT; k++) acc += bdec[k] * wenc[(size_t)k * DICT + j];
    cvec[j] = benc[j] - acc;
}

// ---------------- 4. dead feature scan (dtype-robust) ----------------
__global__ __launch_bounds__(256) void dead_scan(
    const void* __restrict__ dead_raw, int* __restrict__ dead_list, int* __restrict__ ndp)
{
    __shared__ int cnt[256];
    const unsigned char* u8 = (const unsigned char*)dead_raw;
    const unsigned* u32p = (const unsigned*)dead_raw;
    unsigned w0 = u32p[0];
    int mode;                 // 0=int32, 1=u8, 2=f32
    if (w0 == 0x01010101u) mode = 1;
    else if (w0 == 0x3F800000u) mode = 2;
    else if (w0 == 1u) mode = 0;
    else mode = (u8[1] | u8[2] | u8[3]) ? 1 : 0;

    const int t = threadIdx.x;
    const int per = DICT / 256;     // 48
    const int base = t * per;
    int c = 0;
    for (int i = 0; i < per; i++) {
        int j = base + i;
        bool d = (mode == 1) ? (u8[j] != 0)
               : (mode == 2) ? (((const float*)dead_raw)[j] != 0.f)
                             : (((const int*)dead_raw)[j] != 0);
        c += d ? 1 : 0;
    }
    cnt[t] = c;
    __syncthreads();
    if (!t) {
        int run = 0;
        for (int i = 0; i < 256; i++) { int v = cnt[i]; cnt[i] = run; run += v; }
        *ndp = run;
    }
    __syncthreads();
    int o = cnt[t];
    for (int i = 0; i < per; i++) {
        int j = base + i;
        bool d = (mode == 1) ? (u8[j] != 0)
               : (mode == 2) ? (((const float*)dead_raw)[j] != 0.f)
                             : (((const int*)dead_raw)[j] != 0);
        if (d) dead_list[o++] = j;
    }
}

// ---------------- 5. GEMM1 (2-phase dbuf, BK=32) — round-10 proven form ----------------
__global__ __launch_bounds__(256) void gemm1_kernel(
    const unsigned short* __restrict__ A, const unsigned short* __restrict__ Bt,
    const float* __restrict__ cvec, unsigned short* __restrict__ actspre)
{
    __shared__ __align__(16) unsigned short As[2][128 * 32];
    __shared__ __align__(16) unsigned short Bs[2][128 * 32];
    const int tid = threadIdx.x, lane = tid & 63, wave = tid >> 6;
    const int wr = wave >> 1, wc = wave & 1;
    const int lr = lane & 15, lg = lane >> 4;
    // XCD-grouped remap (bijective on [0,3072))
    const int flat = blockIdx.x;
    const int xcd = flat & 7, j = flat >> 3;       // j 0..383
    const int col0 = (xcd * 12 + (j >> 5)) * 128;  // col tile 0..95
    const int row0 = (j & 31) * 128;               // row panel 0..31
    const int nsteps = ACT / 32;      // 24
    f32x4 acc[4][4] = {};

    auto stage = [&](int kt, int b) {
#pragma unroll
        for (int i = 0; i < 2; i++) {
            int c = wave * 2 + i;
            int o = c * 1024;
            int ol = o + lane * 16;
            int r = ol >> 6;
            int cb = (ol & 63) ^ (((r >> 1) & 3) << 4);
            gload16((const char*)A + (size_t)(row0 + r) * (ACT * 2) + kt * 2 + cb,
                    (const char*)As[b] + o);
            gload16((const char*)Bt + (size_t)(col0 + r) * (ACT * 2) + kt * 2 + cb,
                    (const char*)Bs[b] + o);
        }
    };

    stage(0, 0);
    __syncthreads();
    int cur = 0;
    for (int t = 0; t < nsteps; ++t) {
        const int nxt = cur ^ 1;
        if (t + 1 < nsteps) stage((t + 1) * 32, nxt);
        bf8_t af[4], bfr[4];
#pragma unroll
        for (int m = 0; m < 4; m++) {
            int row = wr * 64 + m * 16 + lr;
            af[m] = *(const bf8_t*)((const char*)As[cur] + row * 64 + ((lg * 16) ^ (((row >> 1) & 3) << 4)));
        }
#pragma unroll
        for (int n = 0; n < 4; n++) {
            int col = wc * 64 + n * 16 + lr;
            bfr[n] = *(const bf8_t*)((const char*)Bs[cur] + col * 64 + ((lg * 16) ^ (((col >> 1) & 3) << 4)));
        }
#pragma unroll
        for (int m = 0; m < 4; m++)
#pragma unroll
            for (int n = 0; n < 4; n++)
                acc[m][n] = __builtin_amdgcn_mfma_f32_16x16x32_bf16(af[m], bfr[n], acc[m][n], 0, 0, 0);
        __syncthreads();
        cur = nxt;
    }
#pragma unroll
    for (int m = 0; m < 4; m++) {
        int row = row0 + wr * 64 + m * 16 + lg * 4;
#pragma unroll
        for (int n = 0; n < 4; n++) {
            int col = col0 + wc * 64 + n * 16 + lr;
            float cadd = cvec[col];
#pragma unroll
            for (int r = 0; r < 4; r++) {
                float v = acc[m][n][r] + cadd;
                actspre[(size_t)(row + r) * DICT + col] = f2b(v);
            }
        }
    }
}

// ---------------- 6. row softmax stats + l1/l0 + top-K + aux A-matrices + out_thr ----------------
__global__ __launch_bounds__(256) void softrow_kernel(
    unsigned short* __restrict__ actspre, const float* __restrict__ qtp,
    const int* __restrict__ dead_list, const int* __restrict__ ndp,
    unsigned short* __restrict__ asoft, unsigned short* __restrict__ aaux,
    float* __restrict__ l1row, float* __restrict__ l0row,
    float* __restrict__ out_thr)
{
    __shared__ __align__(16) unsigned short rowv[DICT];
    __shared__ float shf[4];
    __shared__ int shi[4];
    const int t = threadIdx.x, row = blockIdx.x;
    unsigned short* src = actspre + (size_t)row * DICT;
    float* othr = out_thr + (size_t)row * DICT;
    short8 v[6];
    float mx = -1e30f;
#pragma unroll
    for (int i = 0; i < 6; i++) {
        v[i] = *(const short8*)(src + i * 2048 + t * 8);
        *(short8*)(rowv + i * 2048 + t * 8) = v[i];
#pragma unroll
        for (int e = 0; e < 8; e++) mx = fmaxf(mx, b2f((unsigned short)v[i][e]));
    }
    mx = bredmax(mx, shf);
    const float qt = fmaxf(qtp[0], 0.0f);
    float se = 0.f, l1 = 0.f, l0 = 0.f;
#pragma unroll
    for (int i = 0; i < 6; i++) {
        short8 tvv;
        float tvf[8];
#pragma unroll
        for (int e = 0; e < 8; e++) {
            float f = b2f((unsigned short)v[i][e]);
            se += __expf(f - mx);
            float a = fmaxf(f, 0.f);
            float tv = (a > qt) ? a : 0.f;
            l1 += tv;
            l0 += (tv > 0.f) ? 1.f : 0.f;
            tvv[e] = (tv > 0.f) ? v[i][e] : (short)0;   // thresholded bf16 (exact bits)
            tvf[e] = tv;
        }
        *(short8*)(src + i * 2048 + t * 8) = tvv;       // in-place write-back for gemm2
        float* od = othr + i * 2048 + t * 8;
        *(f32x4*)od       = (f32x4){ tvf[0], tvf[1], tvf[2], tvf[3] };
        *(f32x4*)(od + 4) = (f32x4){ tvf[4], tvf[5], tvf[6], tvf[7] };
    }
    se = bredsum(se, shf);
    l1 = bredsum(l1, shf);
    l0 = bredsum(l0, shf);
    if (!t) { l1row[row] = l1; l0row[row] = l0; }

    float inv64 = 64.0f / se;
    int nd = *ndp; if (nd > NDMAX) nd = NDMAX;
    unsigned k16[4]; float av_[4];
#pragma unroll
    for (int i = 0; i < 4; i++) {
        int k = t + i * 256;
        float f = 0.f;
        if (k < nd) {
            int idx = dead_list[k];
            f = b2f(rowv[idx]);
            asoft[(size_t)row * NDMAX + k] = f2b(f * __expf(f - mx) * inv64);
        } else {
            asoft[(size_t)row * NDMAX + k] = 0;
        }
        float a = (k < nd) ? fmaxf(f, 0.f) : 0.f;
        av_[i] = a;
        k16[i] = __float_as_uint(a) >> 16;   // bf16-derived: low 16 bits are zero
    }
    unsigned lo = 0u, hi = 0x7F80u;
    while (hi - lo > 1u) {
        unsigned mid = (lo + hi) >> 1;
        int c = 0;
#pragma unroll
        for (int i = 0; i < 4; i++) c += (k16[i] >= mid) ? 1 : 0;
        c = bredsumi(c, shi);
        if (c >= KTOP) lo = mid; else hi = mid;
    }
#pragma unroll
    for (int i = 0; i < 4; i++) {
        int k = t + i * 256;
        aaux[(size_t)row * NDMAX + k] = f2b((k16[i] >= lo) ? av_[i] : 0.f);
    }
}

// ---------------- 7. gather dead rows of W_dec^T -> [768][NDMAX] ----------------
__global__ __launch_bounds__(256) void wdead_gather(
    const unsigned short* __restrict__ wdec_t, const int* __restrict__ dead_list,
    const int* __restrict__ ndp, unsigned short* __restrict__ wdead)
{
    int n = blockIdx.x;
    int nd = *ndp; if (nd > NDMAX) nd = NDMAX;
    for (int k = threadIdx.x; k < NDMAX; k += 256)
        wdead[(size_t)n * NDMAX + k] = (k < nd) ? wdec_t[(size_t)n * DICT + dead_list[k]] : 0;
}

// ---------------- 8. GEMM2 (split-K=4, 128x128, BK=32, 2-phase dbuf UNROLL-2, bf16 A) ----------------
__global__ __launch_bounds__(256) void gemm2_kernel(
    const unsigned short* __restrict__ Apre, const unsigned short* __restrict__ Bt,
    float* __restrict__ pxrA, float* __restrict__ pxrB)
{
    __shared__ __align__(16) unsigned short As[2][128 * 32];
    __shared__ __align__(16) unsigned short Bs[2][128 * 32];
    const int tid = threadIdx.x, lane = tid & 63, wave = tid >> 6;
    const int wr = wave >> 1, wc = wave & 1;
    const int lr = lane & 15, lg = lane >> 4;
    const int flat = blockIdx.x;
    const int xcd = flat & 7, s = flat >> 3;      // s 0..95
    const int q = s / 6, m_ = s - 6 * q;          // m_ 0..5 = col tile
    const int g = q * 8 + xcd;                    // 0..127 = (row panel, k chunk)
    const int col0 = m_ * 128;
    const int row0 = (g & 31) * 128;
    const int zidx = g >> 5;
    const int kbase = zidx * (DICT / SPLITK2);
    const int nsteps = (DICT / SPLITK2) / 32;     // 96 (even)
    f32x4 acc[4][4] = {};

    auto stage = [&](int kt, int b) {
#pragma unroll
        for (int i = 0; i < 2; i++) {
            int c = wave * 2 + i;
            int o = c * 1024;
            int ol = o + lane * 16;
            int r = ol >> 6;
            int cb = (ol & 63) ^ (((r >> 1) & 3) << 4);
            gload16((const char*)Apre + (size_t)(row0 + r) * (DICT * 2) + (size_t)kt * 2 + cb,
                    (const char*)As[b] + o);
            gload16((const char*)Bt + (size_t)(col0 + r) * (DICT * 2) + (size_t)kt * 2 + cb,
                    (const char*)Bs[b] + o);
        }
    };
    auto compute = [&](int b) {
        bf8_t af[4], bfr[4];
#pragma unroll
        for (int m = 0; m < 4; m++) {
            int row = wr * 64 + m * 16 + lr;
            af[m] = *(const bf8_t*)((const char*)As[b] + row * 64 + ((lg * 16) ^ (((row >> 1) & 3) << 4)));
        }
#pragma unroll
        for (int n = 0; n < 4; n++) {
            int col = wc * 64 + n * 16 + lr;
            bfr[n] = *(const bf8_t*)((const char*)Bs[b] + col * 64 + ((lg * 16) ^ (((col >> 1) & 3) << 4)));
        }
#pragma unroll
        for (int m = 0; m < 4; m++)
#pragma unroll
            for (int n = 0; n < 4; n++)
                acc[m][n] = __builtin_amdgcn_mfma_f32_16x16x32_bf16(af[m], bfr[n], acc[m][n], 0, 0, 0);
    };

    stage(kbase, 0);
    __syncthreads();
    for (int t = 0; t < nsteps; t += 2) {
        stage(kbase + (t + 1) * 32, 1);    // t+1 < nsteps always (nsteps even)
        compute(0);
        __syncthreads();
        if (t + 2 < nsteps) stage(kbase + (t + 2) * 32, 0);
        compute(1);
        __syncthreads();
    }
    float* out = (zidx < 2) ? (pxrA + (size_t)zidx * PLANE)
                            : (pxrB + (size_t)(zidx - 2) * PLANE);
#pragma unroll
    for (int m = 0; m < 4; m++) {
        int row = row0 + wr * 64 + m * 16 + lg * 4;
#pragma unroll
        for (int n = 0; n < 4; n++) {
            int col = col0 + wc * 64 + n * 16 + lr;
#pragma unroll
            for (int r = 0; r < 4; r++)
                out[(size_t)(row + r) * ACT + col] = acc[m][n][r];
        }
    }
}

// ---------------- 9. GEMM3 (dual A, split-K, BK=32, 2-phase dbuf unroll-2) — round-15 form ----------------
__global__ __launch_bounds__(256) void gemm3_kernel(
    const unsigned short* __restrict__ A1, const unsigned short* __restrict__ A2,
    const unsigned short* __restrict__ Bt,
    float* __restrict__ praux, float* __restrict__ prsoft)
{
    __shared__ __align__(16) unsigned short A1s[2][128 * 32];
    __shared__ __align__(16) unsigned short A2s[2][128 * 32];
    __shared__ __align__(16) unsigned short Bs[2][128 * 32];
    const int tid = threadIdx.x, lane = tid & 63, wave = tid >> 6;
    const int wr = wave >> 1, wc = wave & 1;
    const int lr = lane & 15, lg = lane >> 4;
    const int flat = blockIdx.x;
    const int xcd = flat & 7, s = flat >> 3;
    const int q = s / 6, m_ = s - 6 * q;
    const int g = q * 8 + xcd;            // group 0..63
    const int col0 = m_ * 128;
    const int row0 = (g & 31) * 128;
    const int zidx = g >> 5;
    const int kbase = zidx * (NDMAX / SPLITK3);
    const int nsteps = (NDMAX / SPLITK3) / 32;   // 16 (even)
    f32x4 acc1[4][4] = {}, acc2[4][4] = {};

    auto stage = [&](int kt, int b) {
#pragma unroll
        for (int i = 0; i < 2; i++) {
            int c = wave * 2 + i;
            int o = c * 1024;
            int ol = o + lane * 16;
            int r = ol >> 6;
            int cb = (ol & 63) ^ (((r >> 1) & 3) << 4);
            gload16((const char*)A1 + (size_t)(row0 + r) * (NDMAX * 2) + (size_t)kt * 2 + cb,
                    (const char*)A1s[b] + o);
            gload16((const char*)A2 + (size_t)(row0 + r) * (NDMAX * 2) + (size_t)kt * 2 + cb,
                    (const char*)A2s[b] + o);
            gload16((const char*)Bt + (size_t)(col0 + r) * (NDMAX * 2) + (size_t)kt * 2 + cb,
                    (const char*)Bs[b] + o);
        }
    };
    auto compute = [&](int b) {
        bf8_t a1f[4], a2f[4], bfr[4];
#pragma unroll
        for (int m = 0; m < 4; m++) {
            int row = wr * 64 + m * 16 + lr;
            int bo = (lg * 16) ^ (((row >> 1) & 3) << 4);
            a1f[m] = *(const bf8_t*)((const char*)A1s[b] + row * 64 + bo);
            a2f[m] = *(const bf8_t*)((const char*)A2s[b] + row * 64 + bo);
        }
#pragma unroll
        for (int n = 0; n < 4; n++) {
            int col = wc * 64 + n * 16 + lr;
            bfr[n] = *(const bf8_t*)((const char*)Bs[b] + col * 64 + ((lg * 16) ^ (((col >> 1) & 3) << 4)));
        }
#pragma unroll
        for (int m = 0; m < 4; m++)
#pragma unroll
            for (int n = 0; n < 4; n++) {
                acc1[m][n] = __builtin_amdgcn_mfma_f32_16x16x32_bf16(a1f[m], bfr[n], acc1[m][n], 0, 0, 0);
                acc2[m][n] = __builtin_amdgcn_mfma_f32_16x16x32_bf16(a2f[m], bfr[n], acc2[m][n], 0, 0, 0);
            }
    };

    stage(kbase, 0);
    __syncthreads();
    for (int t = 0; t < nsteps; t += 2) {
        stage(kbase + (t + 1) * 32, 1);
        compute(0);
        __syncthreads();
        if (t + 2 < nsteps) stage(kbase + (t + 2) * 32, 0);
        compute(1);
        __syncthreads();
    }
    float* o1 = praux  + (size_t)zidx * PLANE;
    float* o2 = prsoft + (size_t)zidx * PLANE;
#pragma unroll
    for (int m = 0; m < 4; m++) {
        int row = row0 + wr * 64 + m * 16 + lg * 4;
#pragma unroll
        for (int n = 0; n < 4; n++) {
            int col = col0 + wc * 64 + n * 16 + lr;
#pragma unroll
            for (int r = 0; r < 4; r++) {
                size_t idx = (size_t)(row + r) * ACT + col;
                o1[idx] = acc1[m][n][r];
                o2[idx] = acc2[m][n][r];
            }
        }
    }
}

// ---------------- 10. split-K reduce + elementwise epilogue + partial loss sums ----------------
__global__ __launch_bounds__(256) void final_elem(
    const float* __restrict__ pxrA, const float* __restrict__ pxrB,
    const float* __restrict__ praux, const float* __restrict__ prsoft,
    const float* __restrict__ xn, const float* __restrict__ xstd,
    const float* __restrict__ bdec,
    float* __restrict__ sae_out, float* __restrict__ partials)
{
    __shared__ float sh[4];
    const int t = threadIdx.x, blk = blockIdx.x;
    const int base = blk * 2048;
    float s2 = 0.f, sa = 0.f, ss = 0.f;
#pragma unroll
    for (int i = 0; i < 8; i++) {
        int idx = base + t + i * 256;
        int row = idx / ACT;
        int col = idx - row * ACT;
        float bd = bdec[col];
        float r  = pxrA[idx] + pxrA[PLANE + idx] + pxrB[idx] + pxrB[PLANE + idx] + bd;
        float ra = praux[idx] + praux[PLANE + idx] + bd;
        float rs = prsoft[idx] + prsoft[PLANE + idx] + bd;
        float xv = xn[idx];
        float resid = xv - r;
        float da = ra - resid;
        float dsf = rs - resid;
        s2 += resid * resid;
        sa += da * da;
        ss += dsf * dsf;
        sae_out[idx] = r * xstd[row] + xv;
    }
    s2 = bredsum(s2, sh);
    sa = bredsum(sa, sh);
    ss = bredsum(ss, sh);
    if (!t) {
        partials[blk] = s2;
        partials[NBLK_FE + blk] = sa;
        partials[2 * NBLK_FE + blk] = ss;
    }
}

// ---------------- 11. final scalars ----------------
__global__ __launch_bounds__(256) void final_scalar(
    const float* __restrict__ partials, const float* __restrict__ l1row,
    const float* __restrict__ l0row, const int* __restrict__ ndp,
    float* __restrict__ out_sc)
{
    __shared__ float sh[4];
    const int t = threadIdx.x;
    float s2 = 0.f, sa = 0.f, ss = 0.f;
    for (int i = t; i < NBLK_FE; i += 256) {
        s2 += partials[i];
        sa += partials[NBLK_FE + i];
        ss += partials[2 * NBLK_FE + i];
    }
    s2 = bredsum(s2, sh);
    sa = bredsum(sa, sh);
    ss = bredsum(ss, sh);
    float l1 = 0.f, l0 = 0.f;
    for (int i = t; i < B_; i += 256) { l1 += l1row[i]; l0 += l0row[i]; }
    l1 = bredsum(l1, sh);
    l0 = bredsum(l0, sh);
    if (!t) {
        const float n = (float)B_ * (float)ACT;
        float l2   = s2 / n;
        float l2a  = AUX_PEN  * (sa / n);
        float l2s  = SOFT_PEN * (ss / n);
        float l1n  = l1 / (float)B_;
        float l1l  = L1_CO * l1n;
        float l0n  = l0 / (float)B_;
        float loss = l2 + l1l + l2a + l2s;
        out_sc[0] = loss;
        out_sc[1] = l2;
        out_sc[2] = l1l;
        out_sc[3] = l0n;
        out_sc[4] = l1n;
        out_sc[5] = l2a;
        out_sc[6] = l2s;
        out_sc[7] = (float)(*ndp);
    }
}

// ---------------- host launch ----------------
extern "C" void kernel_launch(void* const* d_in, const int* in_sizes, int n_in,
                              void* d_out, int out_size, void* d_ws, size_t ws_size,
                              hipStream_t stream)
{
    const float* x    = (const float*)d_in[0];
    const float* Wenc = (const float*)d_in[1];
    const float* Wdec = (const float*)d_in[2];
    const float* benc = (const float*)d_in[3];
    const float* bdec = (const float*)d_in[4];
    const float* qtp  = (const float*)d_in[5];
    const void*  dead = d_in[6];

    float* out_sae = (float*)d_out;                         // [B_ * ACT]
    float* out_thr = out_sae + (size_t)B_ * ACT;            // [B_ * DICT]
    float* out_sc  = out_thr + (size_t)B_ * DICT;           // [8]

    char* w = (char*)d_ws;
    auto alloc = [&](size_t bytes) -> char* {
        char* p = w;
        w += (bytes + 255) & ~(size_t)255;
        return p;
    };
    float*          xn      = (float*)alloc((size_t)B_ * ACT * 4);
    // xnb and wenc_t are contiguous, dead after gemm1; combined 25,165,824 B = pxr planes 0,1
    unsigned short* xnb     = (unsigned short*)alloc((size_t)B_ * ACT * 2);
    unsigned short* wenc_t  = (unsigned short*)alloc((size_t)DICT * ACT * 2);
    unsigned short* wdec_t  = (unsigned short*)alloc((size_t)ACT * DICT * 2);
    float*          cvec    = (float*)alloc((size_t)DICT * 4);
    unsigned short* actspre = (unsigned short*)alloc((size_t)B_ * DICT * 2);  // 100.66 MB
    unsigned short* asoft   = (unsigned short*)alloc((size_t)B_ * NDMAX * 2);
    unsigned short* aaux    = (unsigned short*)alloc((size_t)B_ * NDMAX * 2);
    unsigned short* wdead   = (unsigned short*)alloc((size_t)ACT * NDMAX * 2);
    float*          xstd    = (float*)alloc((size_t)B_ * 4);
    float*          l1row   = (float*)alloc((size_t)B_ * 4);
    float*          l0row   = (float*)alloc((size_t)B_ * 4);
    float*          partials= (float*)alloc((size_t)3 * NBLK_FE * 4);
    int*            dlist   = (int*)alloc((size_t)DICT * 4);
    int*            ndp     = (int*)alloc(256);
    float*          pxrB    = (float*)alloc((size_t)2 * PLANE * 4);   // pxr planes 2,3

    float* pxrA = (float*)xnb;   // pxr planes 0,1 (xnb+wenc_t, dead after gemm1)
    // gemm3 partial planes alias actspre (gemm3 runs after gemm2's last actspre read)
    float* praux  = (float*)actspre;
    float* prsoft = praux + (size_t)SPLITK3 * PLANE;

    norm_kernel<<<B_, 256, 0, stream>>>(x, xn, xnb, xstd);
    transpose_bf16<<<dim3(DICT / 64, ACT / 64), 256, 0, stream>>>(Wenc, wenc_t, ACT, DICT);
    transpose_bf16<<<dim3(ACT / 64, DICT / 64), 256, 0, stream>>>(Wdec, wdec_t, DICT, ACT);
    cvec_kernel<<<DICT / 256, 256, 0, stream>>>(benc, bdec, Wenc, cvec);
    dead_scan<<<1, 256, 0, stream>>>(dead, dlist, ndp);
    gemm1_kernel<<<3072, 256, 0, stream>>>(xnb, wenc_t, cvec, actspre);
    softrow_kernel<<<B_, 256, 0, stream>>>(actspre, qtp, dlist, ndp, asoft, aaux, l1row, l0row, out_thr);
    wdead_gather<<<ACT, 256, 0, stream>>>(wdec_t, dlist, ndp, wdead);
    gemm2_kernel<<<768, 256, 0, stream>>>(actspre, wdec_t, pxrA, pxrB);
    gemm3_kernel<<<384, 256, 0, stream>>>(aaux, asoft, wdead, praux, prsoft);
    final_elem<<<NBLK_FE, 256, 0, stream>>>(pxrA, pxrB, praux, prsoft, xn, xstd, bdec, out_sae, partials);
    final_scalar<<<1, 256, 0, stream>>>(partials, l1row, l0row, ndp, out_sc);
}